// Round 1
// baseline (216.256 us; speedup 1.0000x reference)
//
#include <hip/hip_runtime.h>
#include <math.h>

#define EPSV 1e-5f

static constexpr int Bb = 2, Ls = 2048, Dd = 256, Hh = 8;
static constexpr int NCH = 32;   // chunks along L
static constexpr int T = 64;     // chunk length

// ---------------- GEMM: C[m][n] = sum_k A[m][k] * W[n][k] + b[n] ----------------
// mode 0: qkv fused (grid.y = 6, writes head-layout [b][h][l][e])
// mode 1: output projection (grid.y = 2, writes plain [m][n])
__global__ __launch_bounds__(256) void gemm_kernel(
    const float* __restrict__ A,
    const float* __restrict__ w0, const float* __restrict__ b0,
    const float* __restrict__ w1, const float* __restrict__ b1,
    const float* __restrict__ w2, const float* __restrict__ b2,
    float* __restrict__ o0, float* __restrict__ o1, float* __restrict__ o2,
    int mode)
{
    constexpr int LDA = 132;             // 128 + 4 pad (keeps float4 alignment, breaks bank conflicts)
    __shared__ float As[16 * LDA];
    __shared__ float Ws[16 * LDA];
    const int tid = threadIdx.x;
    const int mt = blockIdx.x, nt = blockIdx.y;

    const float *Wp, *bp;
    float* Op;
    int ncol0;
    if (mode == 0) {
        const int which = nt >> 1;
        ncol0 = (nt & 1) * 128;
        Wp = which == 0 ? w0 : (which == 1 ? w1 : w2);
        bp = which == 0 ? b0 : (which == 1 ? b1 : b2);
        Op = which == 0 ? o0 : (which == 1 ? o1 : o2);
    } else {
        ncol0 = nt * 128;
        Wp = w0; bp = b0; Op = o0;
    }

    const int tx = tid & 15, ty = tid >> 4;
    const int m0 = mt * 128;
    float acc[8][8] = {};

    for (int k0 = 0; k0 < 256; k0 += 16) {
#pragma unroll
        for (int it = 0; it < 2; ++it) {
            const int idx = it * 256 + tid;
            const int row = idx >> 2;
            const int c4 = (idx & 3) * 4;
            const float4 av = *(const float4*)&A[(size_t)(m0 + row) * 256 + k0 + c4];
            const float4 wv = *(const float4*)&Wp[(size_t)(ncol0 + row) * 256 + k0 + c4];
            As[(c4 + 0) * LDA + row] = av.x;
            As[(c4 + 1) * LDA + row] = av.y;
            As[(c4 + 2) * LDA + row] = av.z;
            As[(c4 + 3) * LDA + row] = av.w;
            Ws[(c4 + 0) * LDA + row] = wv.x;
            Ws[(c4 + 1) * LDA + row] = wv.y;
            Ws[(c4 + 2) * LDA + row] = wv.z;
            Ws[(c4 + 3) * LDA + row] = wv.w;
        }
        __syncthreads();
#pragma unroll
        for (int kk = 0; kk < 16; ++kk) {
            float a[8], w[8];
            *(float4*)&a[0] = *(const float4*)&As[kk * LDA + ty * 8];
            *(float4*)&a[4] = *(const float4*)&As[kk * LDA + ty * 8 + 4];
            *(float4*)&w[0] = *(const float4*)&Ws[kk * LDA + tx * 8];
            *(float4*)&w[4] = *(const float4*)&Ws[kk * LDA + tx * 8 + 4];
#pragma unroll
            for (int i = 0; i < 8; ++i)
#pragma unroll
                for (int j = 0; j < 8; ++j)
                    acc[i][j] = fmaf(a[i], w[j], acc[i][j]);
        }
        __syncthreads();
    }

    float bias[8];
#pragma unroll
    for (int j = 0; j < 8; ++j) bias[j] = bp[ncol0 + tx * 8 + j];

    if (mode == 0) {
#pragma unroll
        for (int i = 0; i < 8; ++i) {
            const int rm = m0 + ty * 8 + i;
            const int b = rm >> 11;          // / L
            const int l = rm & (Ls - 1);
#pragma unroll
            for (int j = 0; j < 8; ++j) {
                const int o = ncol0 + tx * 8 + j;
                const int hd = o >> 5, e = o & 31;
                Op[(((size_t)(b * Hh + hd)) * Ls + l) * 32 + e] = acc[i][j] + bias[j];
            }
        }
    } else {
#pragma unroll
        for (int i = 0; i < 8; ++i) {
            const int rm = m0 + ty * 8 + i;
#pragma unroll
            for (int j = 0; j < 8; ++j) {
                const int o = ncol0 + tx * 8 + j;
                Op[(size_t)rm * 256 + o] = acc[i][j] + bias[j];
            }
        }
    }
}

// ---------------- per-position: sim, l2-normalize k/v (in place), gate ----------------
__global__ __launch_bounds__(256) void pos_kernel(
    const float* __restrict__ qh, float* __restrict__ kh, float* __restrict__ vh,
    const float* __restrict__ wg_w, const float* __restrict__ wg_b,
    const float* __restrict__ kvs, const float* __restrict__ qks,
    float* __restrict__ simv, float* __restrict__ gts)
{
    const int tid = threadIdx.x;
    const int lane = tid & 31;
    const int gpos = blockIdx.x * 8 + (tid >> 5);     // [0, B*H*L)
    const int bh = gpos >> 11;                        // / L
    const int hd = bh & 7;
    const size_t base = (size_t)gpos * 32 + lane;

    const float qv = qh[base];
    const float kv = kh[base];
    const float vv = vh[base];

    float qk = qv * kv, ks = kv * kv, vs = vv * vv;
#pragma unroll
    for (int off = 16; off; off >>= 1) {
        qk += __shfl_xor(qk, off);
        ks += __shfl_xor(ks, off);
        vs += __shfl_xor(vs, off);
    }
    const float kn = kv / fmaxf(sqrtf(ks), 1e-12f);
    const float vn = vv / fmaxf(sqrtf(vs), 1e-12f);
    kh[base] = kn;
    vh[base] = vn;

    // gate logit = sum_{d,e} vn_d * kn_e * W[d*32+e] * kvs[h][d*32+e]
    const float* Krow = kvs + hd * 1024;
    float t = 0.f;
#pragma unroll
    for (int d = 0; d < 32; ++d) {
        const float vd = __shfl(vn, d, 32);
        t = fmaf(vd, wg_w[d * 32 + lane] * Krow[d * 32 + lane], t);
    }
    t *= kn;
#pragma unroll
    for (int off = 16; off; off >>= 1) t += __shfl_xor(t, off);

    if (lane == 0) {
        const float logit = t + wg_b[0];
        const float r = fmaxf(logit, 0.f);
        simv[gpos] = qk * qks[hd];
        gts[gpos] = r * r + EPSV;
    }
}

// ---------------- pass A: per-chunk totals ----------------
__global__ __launch_bounds__(1024) void chunk_sum_kernel(
    const float* __restrict__ kh, const float* __restrict__ vh,
    const float* __restrict__ simv, const float* __restrict__ gts,
    const float* __restrict__ kvs,
    float* __restrict__ Zc, float* __restrict__ mC, float* __restrict__ sC, float* __restrict__ gC)
{
    __shared__ float lkn[T * 32], lvn[T * 32], lg[T], lsim[T];
    const int tid = threadIdx.x;
    const int c = blockIdx.x, bh = blockIdx.y;
    const int hd = bh & 7;
    const size_t base = ((size_t)bh * Ls + c * T) * 32;

    lkn[tid] = kh[base + tid];
    lkn[1024 + tid] = kh[base + 1024 + tid];
    lvn[tid] = vh[base + tid];
    lvn[1024 + tid] = vh[base + 1024 + tid];
    if (tid < T) {
        lg[tid] = gts[bh * Ls + c * T + tid];
        lsim[tid] = simv[bh * Ls + c * T + tid];
    }
    __syncthreads();

    const int d = tid & 31, e = tid >> 5;
    const float kvse = kvs[hd * 1024 + d * 32 + e];
    float z = 0.f;
#pragma unroll 4
    for (int l = 0; l < T; ++l)
        z = fmaf(lg[l] * lvn[l * 32 + d], lkn[l * 32 + e], z);
    Zc[((size_t)bh * NCH + c) * 1024 + tid] = z * kvse;

    if (tid < 64) {
        float m = lsim[tid], s = 1.f, g = lg[tid];
#pragma unroll
        for (int off = 32; off; off >>= 1) {
            const float mo = __shfl_xor(m, off);
            const float so = __shfl_xor(s, off);
            const float mn = fmaxf(m, mo);
            s = s * __expf(m - mn) + so * __expf(mo - mn);
            m = mn;
            g += __shfl_xor(g, off);
        }
        if (tid == 0) {
            mC[bh * NCH + c] = m;
            sC[bh * NCH + c] = s;
            gC[bh * NCH + c] = g;
        }
    }
}

// ---------------- pass B: exclusive prefix over chunks (in place) ----------------
__global__ __launch_bounds__(1024) void prefix_kernel(
    float* __restrict__ Zc, float* __restrict__ mC, float* __restrict__ sC, float* __restrict__ gC)
{
    const int bh = blockIdx.x, tid = threadIdx.x;
    float run = 0.f;
    for (int c = 0; c < NCH; ++c) {
        const size_t idx = ((size_t)bh * NCH + c) * 1024 + tid;
        const float t = Zc[idx];
        Zc[idx] = run;
        run += t;
    }
    if (tid == 0) {
        float m = -1e30f, s = 0.f, g = 0.f;
        for (int c = 0; c < NCH; ++c) {
            const int i = bh * NCH + c;
            const float mc = mC[i], sc = sC[i], gc = gC[i];
            mC[i] = m; sC[i] = s; gC[i] = g;     // exclusive
            const float mn = fmaxf(m, mc);
            s = s * __expf(m - mn) + sc * __expf(mc - mn);
            m = mn;
            g += gc;
        }
    }
}

// ---------------- pass C: replay chunk, emit ctxt ----------------
__global__ __launch_bounds__(1024) void chunk_out_kernel(
    const float* __restrict__ qh, const float* __restrict__ kh, const float* __restrict__ vh,
    const float* __restrict__ simv, const float* __restrict__ gts,
    const float* __restrict__ kvs,
    const float* __restrict__ Zc, const float* __restrict__ mC,
    const float* __restrict__ sC, const float* __restrict__ gC,
    float* __restrict__ ctxt)
{
    __shared__ float lq[T * 32], lkn[T * 32], lvn[T * 32], lc[T * 32];
    __shared__ float lg[T], lsim[T], lw[T];
    const int tid = threadIdx.x;
    const int c = blockIdx.x, bh = blockIdx.y;
    const int b = bh >> 3, hd = bh & 7;
    const size_t base = ((size_t)bh * Ls + c * T) * 32;

    lq[tid] = qh[base + tid];
    lq[1024 + tid] = qh[base + 1024 + tid];
    lkn[tid] = kh[base + tid];
    lkn[1024 + tid] = kh[base + 1024 + tid];
    lvn[tid] = vh[base + tid];
    lvn[1024 + tid] = vh[base + 1024 + tid];
    if (tid < T) {
        lg[tid] = gts[bh * Ls + c * T + tid];
        lsim[tid] = simv[bh * Ls + c * T + tid];
    }
    const int d = tid & 31, e = tid >> 5;
    const float kvse = kvs[hd * 1024 + d * 32 + e];
    float z = Zc[((size_t)bh * NCH + c) * 1024 + tid];
    __syncthreads();

    if (tid < 64) {
        // parallel inclusive scan of (m,s) and g over the 64 chunk positions
        const float m0 = mC[bh * NCH + c], s0 = sC[bh * NCH + c], g0 = gC[bh * NCH + c];
        float m = lsim[tid], s = 1.f, g = lg[tid];
#pragma unroll
        for (int off = 1; off < 64; off <<= 1) {
            const float mo = __shfl_up(m, off);
            const float so = __shfl_up(s, off);
            const float go = __shfl_up(g, off);
            if (tid >= off) {
                const float mn = fmaxf(m, mo);
                s = s * __expf(m - mn) + so * __expf(mo - mn);
                m = mn;
                g += go;
            }
        }
        const float mn = fmaxf(m0, m);
        s = s0 * __expf(m0 - mn) + s * __expf(m - mn);
        m = mn;
        g += g0;
        const float sw = __expf(lsim[tid] - m) / (s + EPSV);
        const float sig = 1.f / (1.f + __expf(-sw));
        lw[tid] = (1.f + sw * sig) / (g + EPSV);
    }
    __syncthreads();

    for (int l = 0; l < T; ++l) {
        z = fmaf(lg[l] * lvn[l * 32 + d] * kvse, lkn[l * 32 + e], z);
        float p = lq[l * 32 + d] * z;
#pragma unroll
        for (int off = 16; off; off >>= 1) p += __shfl_xor(p, off);
        if (d == 0) lc[l * 32 + e] = p * lw[l];
    }
    __syncthreads();

#pragma unroll
    for (int r = 0; r < 2; ++r) {
        const int idx = r * 1024 + tid;
        const int l = idx >> 5, comp = idx & 31;
        ctxt[((size_t)(b * Ls + c * T + l)) * 256 + hd * 32 + comp] = lc[idx];
    }
}

extern "C" void kernel_launch(void* const* d_in, const int* in_sizes, int n_in,
                              void* d_out, int out_size, void* d_ws, size_t ws_size,
                              hipStream_t stream) {
    const float* x    = (const float*)d_in[0];
    const float* wq_w = (const float*)d_in[1];
    const float* wq_b = (const float*)d_in[2];
    const float* wk_w = (const float*)d_in[3];
    const float* wk_b = (const float*)d_in[4];
    const float* wv_w = (const float*)d_in[5];
    const float* wv_b = (const float*)d_in[6];
    const float* wo_w = (const float*)d_in[7];
    const float* wo_b = (const float*)d_in[8];
    const float* wg_w = (const float*)d_in[9];
    const float* wg_b = (const float*)d_in[10];
    const float* kvs  = (const float*)d_in[11];
    const float* qks  = (const float*)d_in[12];
    float* out = (float*)d_out;

    float* ws = (float*)d_ws;
    float* qh   = ws;                    // B*H*L*32 = 1048576
    float* kh   = qh + 1048576;
    float* vh   = kh + 1048576;
    float* simv = vh + 1048576;          // 32768
    float* gts  = simv + 32768;          // 32768
    float* Zc   = gts + 32768;           // 16*32*1024 = 524288
    float* mC   = Zc + 524288;           // 512
    float* sC   = mC + 512;
    float* gC   = sC + 512;
    float* ctxt = gC + 512;              // 1048576
    // total ~19.2 MB of workspace

    gemm_kernel<<<dim3(32, 6), 256, 0, stream>>>(
        x, wq_w, wq_b, wk_w, wk_b, wv_w, wv_b, qh, kh, vh, 0);
    pos_kernel<<<4096, 256, 0, stream>>>(
        qh, kh, vh, wg_w, wg_b, kvs, qks, simv, gts);
    chunk_sum_kernel<<<dim3(NCH, 16), 1024, 0, stream>>>(
        kh, vh, simv, gts, kvs, Zc, mC, sC, gC);
    prefix_kernel<<<16, 1024, 0, stream>>>(Zc, mC, sC, gC);
    chunk_out_kernel<<<dim3(NCH, 16), 1024, 0, stream>>>(
        qh, kh, vh, simv, gts, kvs, Zc, mC, sC, gC, ctxt);
    gemm_kernel<<<dim3(32, 2), 256, 0, stream>>>(
        ctxt, wo_w, wo_b, nullptr, nullptr, nullptr, nullptr, out, nullptr, nullptr, 1);
}

// Round 2
// 215.403 us; speedup vs baseline: 1.0040x; 1.0040x over previous
//
#include <hip/hip_runtime.h>
#include <math.h>

#define EPSV 1e-5f

static constexpr int Ls = 2048, Hh = 8;
static constexpr int NCH = 64, T = 32;   // 64 chunks of 32 along L

// ---------------- GEMM: C[m][n] = sum_k A[m][k] * W[n][k] + b[n], 64x64 tiles ----
// mode 0: qkv fused (grid.y = 12), head-layout output [b][h][l][e]
// mode 1: out-proj (grid.y = 4), plain [m][n]
__global__ __launch_bounds__(256) void gemm_kernel(
    const float* __restrict__ A,
    const float* __restrict__ w0, const float* __restrict__ b0,
    const float* __restrict__ w1, const float* __restrict__ b1,
    const float* __restrict__ w2, const float* __restrict__ b2,
    float* __restrict__ o0, float* __restrict__ o1, float* __restrict__ o2,
    int mode)
{
    constexpr int LDT = 68;
    __shared__ float As[16 * LDT];
    __shared__ float Ws[16 * LDT];
    const int tid = threadIdx.x;
    const int mt = blockIdx.x, nt = blockIdx.y;

    const float *Wp, *bp;
    float* Op;
    int ncol0;
    if (mode == 0) {
        const int which = nt >> 2;
        ncol0 = (nt & 3) * 64;
        Wp = which == 0 ? w0 : (which == 1 ? w1 : w2);
        bp = which == 0 ? b0 : (which == 1 ? b1 : b2);
        Op = which == 0 ? o0 : (which == 1 ? o1 : o2);
    } else {
        ncol0 = nt * 64;
        Wp = w0; bp = b0; Op = o0;
    }

    const int tx = tid & 15, ty = tid >> 4;
    const int m0 = mt * 64;
    const int lrow = tid >> 2, lc4 = (tid & 3) * 4;
    float acc[4][4] = {};

    for (int k0 = 0; k0 < 256; k0 += 16) {
        const float4 av = *(const float4*)&A[(size_t)(m0 + lrow) * 256 + k0 + lc4];
        const float4 wv = *(const float4*)&Wp[(size_t)(ncol0 + lrow) * 256 + k0 + lc4];
        As[(lc4 + 0) * LDT + lrow] = av.x;
        As[(lc4 + 1) * LDT + lrow] = av.y;
        As[(lc4 + 2) * LDT + lrow] = av.z;
        As[(lc4 + 3) * LDT + lrow] = av.w;
        Ws[(lc4 + 0) * LDT + lrow] = wv.x;
        Ws[(lc4 + 1) * LDT + lrow] = wv.y;
        Ws[(lc4 + 2) * LDT + lrow] = wv.z;
        Ws[(lc4 + 3) * LDT + lrow] = wv.w;
        __syncthreads();
#pragma unroll
        for (int kk = 0; kk < 16; ++kk) {
            const float4 a4 = *(const float4*)&As[kk * LDT + ty * 4];
            const float4 w4 = *(const float4*)&Ws[kk * LDT + tx * 4];
            const float a[4] = {a4.x, a4.y, a4.z, a4.w};
            const float w[4] = {w4.x, w4.y, w4.z, w4.w};
#pragma unroll
            for (int i = 0; i < 4; ++i)
#pragma unroll
                for (int j = 0; j < 4; ++j)
                    acc[i][j] = fmaf(a[i], w[j], acc[i][j]);
        }
        __syncthreads();
    }

    float bias[4];
#pragma unroll
    for (int j = 0; j < 4; ++j) bias[j] = bp[ncol0 + tx * 4 + j];

    if (mode == 0) {
#pragma unroll
        for (int i = 0; i < 4; ++i) {
            const int rm = m0 + ty * 4 + i;
            const int b = rm >> 11, l = rm & (Ls - 1);
#pragma unroll
            for (int j = 0; j < 4; ++j) {
                const int o = ncol0 + tx * 4 + j;
                const int hd = o >> 5, e = o & 31;
                Op[(((size_t)(b * Hh + hd)) * Ls + l) * 32 + e] = acc[i][j] + bias[j];
            }
        }
    } else {
#pragma unroll
        for (int i = 0; i < 4; ++i) {
            const int rm = m0 + ty * 4 + i;
#pragma unroll
            for (int j = 0; j < 4; ++j)
                Op[(size_t)rm * 256 + ncol0 + tx * 4 + j] = acc[i][j] + bias[j];
        }
    }
}

// ---------------- setup: detect rank-1 kv_norm_scale, extract a,b ----------------
__global__ __launch_bounds__(256) void setup_kernel(
    const float* __restrict__ kvs, float* __restrict__ aW, float* __restrict__ bW,
    int* __restrict__ flagW)
{
    const int tid = threadIdx.x;       // 256 = 8 heads x 32
    const int h = tid >> 5, e = tid & 31;
    const float* K = kvs + h * 1024;
    const float k00 = K[0];
    int ok = (k00 != 0.0f);
    for (int d = 0; d < 32; ++d) {
        const float lhs = K[d * 32 + e] * k00;
        const float rhs = K[d * 32] * K[e];
        const float diff = fabsf(lhs - rhs);
        if (diff > 1e-6f * fmaxf(fmaxf(fabsf(lhs), fabsf(rhs)), 1e-20f)) ok = 0;
    }
    aW[h * 32 + e] = K[e * 32];                       // a[d] = kvs[d][0]
    bW[h * 32 + e] = (k00 != 0.0f) ? K[e] / k00 : 0.f; // b[e] = kvs[0][e]/kvs[0][0]
    const int allok = __syncthreads_and(ok);
    if (tid == 0) flagW[0] = allok;
}

// ---------------- chunk_sum: normalize k/v (in place), sim, gates, chunk totals ----
__global__ __launch_bounds__(1024) void chunk_sum_kernel(
    const float* __restrict__ qh, float* __restrict__ kh, float* __restrict__ vh,
    const float* __restrict__ wg_w, const float* __restrict__ wg_b,
    const float* __restrict__ kvs, const float* __restrict__ qks,
    float* __restrict__ simG, float* __restrict__ gG,
    float* __restrict__ ZcT, float* __restrict__ mT, float* __restrict__ sT,
    float* __restrict__ gTt)
{
    __shared__ float lkn[1024], lvn[1024], lwk[1024], lsim[T], lg[T];
    const int tid = threadIdx.x;
    const int c = blockIdx.x, bh = blockIdx.y, h = bh & 7;
    const int l = tid >> 5, lane = tid & 31;
    const size_t base = ((size_t)bh * Ls + c * T) * 32;

    const float qv = qh[base + tid];
    const float kv = kh[base + tid];
    const float vv = vh[base + tid];
    lwk[tid] = wg_w[tid] * kvs[h * 1024 + tid];

    float qk = qv * kv, ks = kv * kv, vs = vv * vv;
#pragma unroll
    for (int off = 16; off; off >>= 1) {
        qk += __shfl_xor(qk, off);
        ks += __shfl_xor(ks, off);
        vs += __shfl_xor(vs, off);
    }
    const float kn = kv / fmaxf(sqrtf(ks), 1e-12f);
    const float vn = vv / fmaxf(sqrtf(vs), 1e-12f);
    kh[base + tid] = kn;      // in-place: element owned by this thread only
    vh[base + tid] = vn;
    lkn[tid] = kn;
    lvn[tid] = vn;
    if (lane == 0) {
        const float s = qk * qks[h];
        lsim[l] = s;
        simG[bh * Ls + c * T + l] = s;
    }
    __syncthreads();

    // gate[l] = relu(sum_e kn_e * sum_d vn_d * (W*kvs)[d,e] + bias)^2 + eps
    float t = 0.f;
#pragma unroll 8
    for (int d = 0; d < 32; ++d)
        t = fmaf(lvn[l * 32 + d], lwk[d * 32 + lane], t);
    t *= lkn[l * 32 + lane];
#pragma unroll
    for (int off = 16; off; off >>= 1) t += __shfl_xor(t, off);
    if (lane == 0) {
        const float r = fmaxf(t + wg_b[0], 0.f);
        const float g = r * r + EPSV;
        lg[l] = g;
        gG[bh * Ls + c * T + l] = g;
    }
    __syncthreads();

    // raw chunk Z total (no kvs): Z[d][e] = sum_l g[l]*vn[l,d]*kn[l,e]
    {
        const int e = tid & 31, d = tid >> 5;
        float z = 0.f;
#pragma unroll 8
        for (int l2 = 0; l2 < T; ++l2)
            z = fmaf(lg[l2] * lvn[l2 * 32 + d], lkn[l2 * 32 + e], z);
        ZcT[((size_t)bh * NCH + c) * 1024 + tid] = z;
    }

    // (m,s,g) chunk totals by warp 0
    if (tid < 32) {
        float m = lsim[tid], s = 1.f, g = lg[tid];
#pragma unroll
        for (int off = 16; off; off >>= 1) {
            const float mo = __shfl_xor(m, off);
            const float so = __shfl_xor(s, off);
            const float mn = fmaxf(m, mo);
            s = s * __expf(m - mn) + so * __expf(mo - mn);
            m = mn;
            g += __shfl_xor(g, off);
        }
        if (tid == 0) {
            mT[bh * NCH + c] = m;
            sT[bh * NCH + c] = s;
            gTt[bh * NCH + c] = g;
        }
    }
}

// ---------------- chunk_out: per-chunk matmul-shaped replay, emit ctxt ----------------
__global__ __launch_bounds__(1024) void chunk_out_kernel(
    const float* __restrict__ qh, const float* __restrict__ knG, const float* __restrict__ vnG,
    const float* __restrict__ simG, const float* __restrict__ gG,
    const float* __restrict__ kvs,
    const float* __restrict__ ZcT, const float* __restrict__ mT,
    const float* __restrict__ sT, const float* __restrict__ gTt,
    const float* __restrict__ aW, const float* __restrict__ bW,
    const int* __restrict__ flagW,
    float* __restrict__ ctxt)
{
    __shared__ float qa[1024], knb[1024], zp[1024], lkvs[1024];
    __shared__ float vnT[32 * 33], sW[32 * 33];
    __shared__ float la[32], lb[32], lg[T], lsim[T], lwgt[T];
    const int tid = threadIdx.x;
    const int c = blockIdx.x, bh = blockIdx.y, h = bh & 7, b = bh >> 3;
    const int l = tid >> 5, lane = tid & 31;
    const size_t base = ((size_t)bh * Ls + c * T) * 32;
    const int flag = flagW[0];

    const float qv = qh[base + tid];
    const float knv = knG[base + tid];
    const float vnv = vnG[base + tid];
    vnT[lane * 33 + l] = vnv;                       // transposed v
    if (!flag) lkvs[tid] = kvs[h * 1024 + tid];
    if (tid < 32) {
        la[tid] = aW[h * 32 + tid];
        lb[tid] = bW[h * 32 + tid];
        lg[tid] = gG[bh * Ls + c * T + tid];
        lsim[tid] = simG[bh * Ls + c * T + tid];
    }
    // Z prefix (raw) from chunk totals
    float zacc = 0.f;
    for (int cp = 0; cp < c; ++cp)
        zacc += ZcT[((size_t)bh * NCH + cp) * 1024 + tid];
    zp[tid] = zacc;
    __syncthreads();

    qa[tid] = flag ? qv * la[lane] : qv;
    knb[tid] = flag ? knv * lb[lane] : knv;
    if (tid < 32) {
        // inclusive (m,s,g) scan within chunk
        float m = lsim[tid], s = 1.f, g = lg[tid];
#pragma unroll
        for (int off = 1; off < 32; off <<= 1) {
            const float mo = __shfl_up(m, off);
            const float so = __shfl_up(s, off);
            const float go = __shfl_up(g, off);
            if (tid >= off) {
                const float mn = fmaxf(m, mo);
                s = s * __expf(m - mn) + so * __expf(mo - mn);
                m = mn;
                g += go;
            }
        }
        // exclusive chunk prefix (lane-redundant serial)
        float mp = -1e30f, sp = 0.f, gp = 0.f;
        for (int cp = 0; cp < c; ++cp) {
            const float mc = mT[bh * NCH + cp];
            const float sc = sT[bh * NCH + cp];
            const float gc = gTt[bh * NCH + cp];
            const float mn = fmaxf(mp, mc);
            sp = sp * __expf(mp - mn) + sc * __expf(mc - mn);
            mp = mn;
            gp += gc;
        }
        const float mn = fmaxf(mp, m);
        s = sp * __expf(mp - mn) + s * __expf(m - mn);
        m = mn;
        g += gp;
        const float sw = __expf(lsim[tid] - m) / (s + EPSV);
        const float sig = 1.f / (1.f + __expf(-sw));
        lwgt[tid] = (1.f + sw * sig) / (g + EPSV);
    }
    __syncthreads();

    if (flag) {
        // fast path (kvs = a x b): S = (q.a) V^T  then causal-masked S.K
        float s = 0.f, y0 = 0.f;
        const float4* qa4 = (const float4*)&qa[l * 32];
#pragma unroll
        for (int d4 = 0; d4 < 8; ++d4) {
            const float4 q4 = qa4[d4];
            const int d = d4 * 4;
            s = fmaf(q4.x, vnT[(d + 0) * 33 + lane], s);
            s = fmaf(q4.y, vnT[(d + 1) * 33 + lane], s);
            s = fmaf(q4.z, vnT[(d + 2) * 33 + lane], s);
            s = fmaf(q4.w, vnT[(d + 3) * 33 + lane], s);
            y0 = fmaf(q4.x, zp[(d + 0) * 32 + lane], y0);
            y0 = fmaf(q4.y, zp[(d + 1) * 32 + lane], y0);
            y0 = fmaf(q4.z, zp[(d + 2) * 32 + lane], y0);
            y0 = fmaf(q4.w, zp[(d + 3) * 32 + lane], y0);
        }
        sW[l * 33 + lane] = (lane <= l) ? lg[lane] * s : 0.f;
        __syncthreads();
        float y = y0 * lb[lane];
#pragma unroll 8
        for (int j = 0; j < 32; ++j)
            y = fmaf(sW[l * 33 + j], knb[j * 32 + lane], y);
        y *= lwgt[l];
        ctxt[((size_t)(b * Ls + c * T + l)) * 256 + h * 32 + lane] = y;
    } else {
        // general kvs fallback (e-replicated scores)
        float qe[32];
#pragma unroll
        for (int d = 0; d < 32; ++d)
            qe[d] = qa[l * 32 + d] * lkvs[d * 32 + lane];
        float y = 0.f;
#pragma unroll
        for (int d = 0; d < 32; ++d)
            y = fmaf(qe[d], zp[d * 32 + lane], y);
        for (int j = 0; j < 32; ++j) {
            float s = 0.f;
#pragma unroll
            for (int d = 0; d < 32; ++d)
                s = fmaf(qe[d], vnT[d * 33 + j], s);
            if (j <= l) y = fmaf(lg[j] * s, knb[j * 32 + lane], y);
        }
        y *= lwgt[l];
        ctxt[((size_t)(b * Ls + c * T + l)) * 256 + h * 32 + lane] = y;
    }
}

extern "C" void kernel_launch(void* const* d_in, const int* in_sizes, int n_in,
                              void* d_out, int out_size, void* d_ws, size_t ws_size,
                              hipStream_t stream) {
    const float* x    = (const float*)d_in[0];
    const float* wq_w = (const float*)d_in[1];
    const float* wq_b = (const float*)d_in[2];
    const float* wk_w = (const float*)d_in[3];
    const float* wk_b = (const float*)d_in[4];
    const float* wv_w = (const float*)d_in[5];
    const float* wv_b = (const float*)d_in[6];
    const float* wo_w = (const float*)d_in[7];
    const float* wo_b = (const float*)d_in[8];
    const float* wg_w = (const float*)d_in[9];
    const float* wg_b = (const float*)d_in[10];
    const float* kvs  = (const float*)d_in[11];
    const float* qks  = (const float*)d_in[12];
    float* out = (float*)d_out;

    float* ws = (float*)d_ws;
    float* qh   = out;                    // d_out doubles as q scratch (1M floats)
    float* kh   = ws;                     // 1048576
    float* vh   = kh + 1048576;           // 1048576
    float* simG = vh + 1048576;           // 32768
    float* gG   = simG + 32768;           // 32768
    float* ZcT  = gG + 32768;             // 16*64*1024 = 1048576
    float* mT   = ZcT + 1048576;          // 1024
    float* sT   = mT + 1024;              // 1024
    float* gTt  = sT + 1024;              // 1024
    float* aW   = gTt + 1024;             // 256
    float* bW   = aW + 256;               // 256
    int*   flagW = (int*)(bW + 256);      // 4 floats reserved
    float* ctxt = bW + 256 + 4;           // 1048576
    // total ~17.1 MB

    setup_kernel<<<1, 256, 0, stream>>>(kvs, aW, bW, flagW);
    gemm_kernel<<<dim3(64, 12), 256, 0, stream>>>(
        x, wq_w, wq_b, wk_w, wk_b, wv_w, wv_b, qh, kh, vh, 0);
    chunk_sum_kernel<<<dim3(NCH, 16), 1024, 0, stream>>>(
        qh, kh, vh, wg_w, wg_b, kvs, qks, simG, gG, ZcT, mT, sT, gTt);
    chunk_out_kernel<<<dim3(NCH, 16), 1024, 0, stream>>>(
        qh, kh, vh, simG, gG, kvs, ZcT, mT, sT, gTt, aW, bW, flagW, ctxt);
    gemm_kernel<<<dim3(64, 4), 256, 0, stream>>>(
        ctxt, wo_w, wo_b, nullptr, nullptr, nullptr, nullptr, out, nullptr, nullptr, 1);
}

// Round 3
// 161.880 us; speedup vs baseline: 1.3359x; 1.3306x over previous
//
#include <hip/hip_runtime.h>
#include <math.h>

#define EPSV 1e-5f

static constexpr int Ls = 2048, Hh = 8;
static constexpr int NCH = 64, T = 32;   // 64 chunks of 32 along L

// ---------------- GEMM: C[m][n] = sum_k A[m][k] * W[n][k] + b[n], 64x64 tiles ----
// mode 0: qkv fused (grid.y = 12), head-layout output [b][h][l][e]
// mode 1: out-proj (grid.y = 4), plain [m][n]
__global__ __launch_bounds__(256) void gemm_kernel(
    const float* __restrict__ A,
    const float* __restrict__ w0, const float* __restrict__ b0,
    const float* __restrict__ w1, const float* __restrict__ b1,
    const float* __restrict__ w2, const float* __restrict__ b2,
    float* __restrict__ o0, float* __restrict__ o1, float* __restrict__ o2,
    int mode)
{
    constexpr int LDT = 68;
    __shared__ float As[16 * LDT];
    __shared__ float Ws[16 * LDT];
    const int tid = threadIdx.x;
    const int mt = blockIdx.x, nt = blockIdx.y;

    const float *Wp, *bp;
    float* Op;
    int ncol0;
    if (mode == 0) {
        const int which = nt >> 2;
        ncol0 = (nt & 3) * 64;
        Wp = which == 0 ? w0 : (which == 1 ? w1 : w2);
        bp = which == 0 ? b0 : (which == 1 ? b1 : b2);
        Op = which == 0 ? o0 : (which == 1 ? o1 : o2);
    } else {
        ncol0 = nt * 64;
        Wp = w0; bp = b0; Op = o0;
    }

    const int tx = tid & 15, ty = tid >> 4;
    const int m0 = mt * 64;
    const int lrow = tid >> 2, lc4 = (tid & 3) * 4;
    float acc[4][4] = {};

    for (int k0 = 0; k0 < 256; k0 += 16) {
        const float4 av = *(const float4*)&A[(size_t)(m0 + lrow) * 256 + k0 + lc4];
        const float4 wv = *(const float4*)&Wp[(size_t)(ncol0 + lrow) * 256 + k0 + lc4];
        As[(lc4 + 0) * LDT + lrow] = av.x;
        As[(lc4 + 1) * LDT + lrow] = av.y;
        As[(lc4 + 2) * LDT + lrow] = av.z;
        As[(lc4 + 3) * LDT + lrow] = av.w;
        Ws[(lc4 + 0) * LDT + lrow] = wv.x;
        Ws[(lc4 + 1) * LDT + lrow] = wv.y;
        Ws[(lc4 + 2) * LDT + lrow] = wv.z;
        Ws[(lc4 + 3) * LDT + lrow] = wv.w;
        __syncthreads();
#pragma unroll
        for (int kk = 0; kk < 16; ++kk) {
            const float4 a4 = *(const float4*)&As[kk * LDT + ty * 4];
            const float4 w4 = *(const float4*)&Ws[kk * LDT + tx * 4];
            const float a[4] = {a4.x, a4.y, a4.z, a4.w};
            const float w[4] = {w4.x, w4.y, w4.z, w4.w};
#pragma unroll
            for (int i = 0; i < 4; ++i)
#pragma unroll
                for (int j = 0; j < 4; ++j)
                    acc[i][j] = fmaf(a[i], w[j], acc[i][j]);
        }
        __syncthreads();
    }

    float bias[4];
#pragma unroll
    for (int j = 0; j < 4; ++j) bias[j] = bp[ncol0 + tx * 4 + j];

    if (mode == 0) {
#pragma unroll
        for (int i = 0; i < 4; ++i) {
            const int rm = m0 + ty * 4 + i;
            const int b = rm >> 11, l = rm & (Ls - 1);
#pragma unroll
            for (int j = 0; j < 4; ++j) {
                const int o = ncol0 + tx * 4 + j;
                const int hd = o >> 5, e = o & 31;
                Op[(((size_t)(b * Hh + hd)) * Ls + l) * 32 + e] = acc[i][j] + bias[j];
            }
        }
    } else {
#pragma unroll
        for (int i = 0; i < 4; ++i) {
            const int rm = m0 + ty * 4 + i;
#pragma unroll
            for (int j = 0; j < 4; ++j)
                Op[(size_t)rm * 256 + ncol0 + tx * 4 + j] = acc[i][j] + bias[j];
        }
    }
}

// ---------------- chunk_sum: normalize k/v (in place), sim, gates, chunk totals ----
__global__ __launch_bounds__(1024) void chunk_sum_kernel(
    const float* __restrict__ qh, float* __restrict__ kh, float* __restrict__ vh,
    const float* __restrict__ wg_w, const float* __restrict__ wg_b,
    const float* __restrict__ kvs, const float* __restrict__ qks,
    float* __restrict__ simG, float* __restrict__ gG,
    float* __restrict__ ZcT, float* __restrict__ mT, float* __restrict__ sT,
    float* __restrict__ gTt)
{
    __shared__ float lkn[1024], lvn[1024], lwk[1024], lsim[T], lg[T];
    const int tid = threadIdx.x;
    const int c = blockIdx.x, bh = blockIdx.y, h = bh & 7;
    const int l = tid >> 5, lane = tid & 31;
    const size_t base = ((size_t)bh * Ls + c * T) * 32;

    const float qv = qh[base + tid];
    const float kv = kh[base + tid];
    const float vv = vh[base + tid];
    lwk[tid] = wg_w[tid] * kvs[h * 1024 + tid];

    float qk = qv * kv, ks = kv * kv, vs = vv * vv;
#pragma unroll
    for (int off = 16; off; off >>= 1) {
        qk += __shfl_xor(qk, off);
        ks += __shfl_xor(ks, off);
        vs += __shfl_xor(vs, off);
    }
    const float kn = kv / fmaxf(sqrtf(ks), 1e-12f);
    const float vn = vv / fmaxf(sqrtf(vs), 1e-12f);
    kh[base + tid] = kn;      // in-place: element owned by this thread only
    vh[base + tid] = vn;
    lkn[tid] = kn;
    lvn[tid] = vn;
    if (lane == 0) {
        const float s = qk * qks[h];
        lsim[l] = s;
        simG[bh * Ls + c * T + l] = s;
    }
    __syncthreads();

    // gate[l] = relu(sum_e kn_e * sum_d vn_d * (W*kvs)[d,e] + bias)^2 + eps
    float t = 0.f;
#pragma unroll 8
    for (int d = 0; d < 32; ++d)
        t = fmaf(lvn[l * 32 + d], lwk[d * 32 + lane], t);
    t *= lkn[l * 32 + lane];
#pragma unroll
    for (int off = 16; off; off >>= 1) t += __shfl_xor(t, off);
    if (lane == 0) {
        const float r = fmaxf(t + wg_b[0], 0.f);
        const float g = r * r + EPSV;
        lg[l] = g;
        gG[bh * Ls + c * T + l] = g;
    }
    __syncthreads();

    // raw chunk Z total (no kvs): Z[d][e] = sum_l g[l]*vn[l,d]*kn[l,e]
    {
        const int e = tid & 31, d = tid >> 5;
        float z = 0.f;
#pragma unroll 8
        for (int l2 = 0; l2 < T; ++l2)
            z = fmaf(lg[l2] * lvn[l2 * 32 + d], lkn[l2 * 32 + e], z);
        ZcT[((size_t)bh * NCH + c) * 1024 + tid] = z;
    }

    // (m,s,g) chunk totals by warp 0
    if (tid < 32) {
        float m = lsim[tid], s = 1.f, g = lg[tid];
#pragma unroll
        for (int off = 16; off; off >>= 1) {
            const float mo = __shfl_xor(m, off);
            const float so = __shfl_xor(s, off);
            const float mn = fmaxf(m, mo);
            s = s * __expf(m - mn) + so * __expf(mo - mn);
            m = mn;
            g += __shfl_xor(g, off);
        }
        if (tid == 0) {
            mT[bh * NCH + c] = m;
            sT[bh * NCH + c] = s;
            gTt[bh * NCH + c] = g;
        }
    }
}

// ---------------- prefix: in-place exclusive prefixes over chunks + rank-1 setup ----
// grid (16 bh, 4 seg) x 256 threads. Z-prefix: batched independent loads.
// (m,s,g): one wave64 shuffle scan. Block (0,3) additionally runs kvs rank-1 setup.
__global__ __launch_bounds__(256) void prefix_kernel(
    float* __restrict__ Zc, float* __restrict__ mT, float* __restrict__ sT,
    float* __restrict__ gTt,
    const float* __restrict__ kvs, float* __restrict__ aW, float* __restrict__ bW,
    int* __restrict__ flagW)
{
    const int bh = blockIdx.x, seg = blockIdx.y;
    const int tid = threadIdx.x;
    const int el = seg * 256 + tid;
    float* Zb = Zc + (size_t)bh * NCH * 1024 + el;

    float run = 0.f;
#pragma unroll
    for (int cb = 0; cb < NCH; cb += 8) {
        float v[8];
#pragma unroll
        for (int i = 0; i < 8; ++i) v[i] = Zb[(size_t)(cb + i) * 1024];
#pragma unroll
        for (int i = 0; i < 8; ++i) {
            const float t = v[i];
            Zb[(size_t)(cb + i) * 1024] = run;   // exclusive
            run += t;
        }
    }

    if (seg == 0 && tid < 64) {
        // wave64 inclusive scan of (m,s) softmax-combine and g sum over 64 chunks
        float m = mT[bh * NCH + tid], s = sT[bh * NCH + tid], g = gTt[bh * NCH + tid];
#pragma unroll
        for (int off = 1; off < 64; off <<= 1) {
            const float mo = __shfl_up(m, off);
            const float so = __shfl_up(s, off);
            const float go = __shfl_up(g, off);
            if (tid >= off) {
                const float mn = fmaxf(m, mo);
                s = s * __expf(m - mn) + so * __expf(mo - mn);
                m = mn;
                g += go;
            }
        }
        // shift to exclusive
        float me = __shfl_up(m, 1), se = __shfl_up(s, 1), ge = __shfl_up(g, 1);
        if (tid == 0) { me = -1e30f; se = 0.f; ge = 0.f; }
        mT[bh * NCH + tid] = me;
        sT[bh * NCH + tid] = se;
        gTt[bh * NCH + tid] = ge;
    }

    if (bh == 0 && seg == 3) {
        // rank-1 detection for kv_norm_scale; extract a (d-vector), b (e-vector)
        const int h = tid >> 5, e = tid & 31;
        const float* K = kvs + h * 1024;
        const float k00 = K[0];
        int ok = (k00 != 0.0f);
        for (int d = 0; d < 32; ++d) {
            const float lhs = K[d * 32 + e] * k00;
            const float rhs = K[d * 32] * K[e];
            const float diff = fabsf(lhs - rhs);
            if (diff > 1e-6f * fmaxf(fmaxf(fabsf(lhs), fabsf(rhs)), 1e-20f)) ok = 0;
        }
        aW[h * 32 + e] = K[e * 32];                        // a[d] = kvs[d][0]
        bW[h * 32 + e] = (k00 != 0.0f) ? K[e] / k00 : 0.f; // b[e] = kvs[0][e]/kvs[0][0]
        const int allok = __syncthreads_and(ok);
        if (tid == 0) flagW[0] = allok;
    }
}

// ---------------- chunk_out: per-chunk matmul-shaped replay, emit ctxt ----------------
__global__ __launch_bounds__(1024) void chunk_out_kernel(
    const float* __restrict__ qh, const float* __restrict__ knG, const float* __restrict__ vnG,
    const float* __restrict__ simG, const float* __restrict__ gG,
    const float* __restrict__ kvs,
    const float* __restrict__ ZcP, const float* __restrict__ mP,
    const float* __restrict__ sP, const float* __restrict__ gP,
    const float* __restrict__ aW, const float* __restrict__ bW,
    const int* __restrict__ flagW,
    float* __restrict__ ctxt)
{
    __shared__ float qa[1024], knb[1024], zp[1024], lkvs[1024];
    __shared__ float vnT[32 * 33], sW[32 * 33];
    __shared__ float la[32], lb[32], lg[T], lsim[T], lwgt[T];
    const int tid = threadIdx.x;
    const int c = blockIdx.x, bh = blockIdx.y, h = bh & 7, b = bh >> 3;
    const int l = tid >> 5, lane = tid & 31;
    const size_t base = ((size_t)bh * Ls + c * T) * 32;
    const int flag = flagW[0];

    const float qv = qh[base + tid];
    const float knv = knG[base + tid];
    const float vnv = vnG[base + tid];
    vnT[lane * 33 + l] = vnv;                       // transposed v
    zp[tid] = ZcP[((size_t)bh * NCH + c) * 1024 + tid];   // exclusive Z prefix
    if (!flag) lkvs[tid] = kvs[h * 1024 + tid];
    if (tid < 32) {
        la[tid] = aW[h * 32 + tid];
        lb[tid] = bW[h * 32 + tid];
        lg[tid] = gG[bh * Ls + c * T + tid];
        lsim[tid] = simG[bh * Ls + c * T + tid];
    }
    __syncthreads();

    qa[tid] = flag ? qv * la[lane] : qv;
    knb[tid] = flag ? knv * lb[lane] : knv;
    if (tid < 32) {
        // inclusive (m,s,g) scan within chunk (parallel, log steps)
        float m = lsim[tid], s = 1.f, g = lg[tid];
#pragma unroll
        for (int off = 1; off < 32; off <<= 1) {
            const float mo = __shfl_up(m, off);
            const float so = __shfl_up(s, off);
            const float go = __shfl_up(g, off);
            if (tid >= off) {
                const float mn = fmaxf(m, mo);
                s = s * __expf(m - mn) + so * __expf(mo - mn);
                m = mn;
                g += go;
            }
        }
        // combine with exclusive chunk-level prefix (precomputed, scalar loads)
        const float mp = mP[bh * NCH + c];
        const float sp = sP[bh * NCH + c];
        const float gp = gP[bh * NCH + c];
        const float mn = fmaxf(mp, m);
        s = sp * __expf(mp - mn) + s * __expf(m - mn);
        m = mn;
        g += gp;
        const float sw = __expf(lsim[tid] - m) / (s + EPSV);
        const float sig = 1.f / (1.f + __expf(-sw));
        lwgt[tid] = (1.f + sw * sig) / (g + EPSV);
    }
    __syncthreads();

    if (flag) {
        // fast path (kvs = a x b): S = (q.a) V^T  then causal-masked S.K
        float s = 0.f, y0 = 0.f;
        const float4* qa4 = (const float4*)&qa[l * 32];
#pragma unroll
        for (int d4 = 0; d4 < 8; ++d4) {
            const float4 q4 = qa4[d4];
            const int d = d4 * 4;
            s = fmaf(q4.x, vnT[(d + 0) * 33 + lane], s);
            s = fmaf(q4.y, vnT[(d + 1) * 33 + lane], s);
            s = fmaf(q4.z, vnT[(d + 2) * 33 + lane], s);
            s = fmaf(q4.w, vnT[(d + 3) * 33 + lane], s);
            y0 = fmaf(q4.x, zp[(d + 0) * 32 + lane], y0);
            y0 = fmaf(q4.y, zp[(d + 1) * 32 + lane], y0);
            y0 = fmaf(q4.z, zp[(d + 2) * 32 + lane], y0);
            y0 = fmaf(q4.w, zp[(d + 3) * 32 + lane], y0);
        }
        sW[l * 33 + lane] = (lane <= l) ? lg[lane] * s : 0.f;
        __syncthreads();
        float y = y0 * lb[lane];
#pragma unroll 8
        for (int j = 0; j < 32; ++j)
            y = fmaf(sW[l * 33 + j], knb[j * 32 + lane], y);
        y *= lwgt[l];
        ctxt[((size_t)(b * Ls + c * T + l)) * 256 + h * 32 + lane] = y;
    } else {
        // general kvs fallback (e-replicated scores)
        float qe[32];
#pragma unroll
        for (int d = 0; d < 32; ++d)
            qe[d] = qa[l * 32 + d] * lkvs[d * 32 + lane];
        float y = 0.f;
#pragma unroll
        for (int d = 0; d < 32; ++d)
            y = fmaf(qe[d], zp[d * 32 + lane], y);
        for (int j = 0; j < 32; ++j) {
            float s = 0.f;
#pragma unroll
            for (int d = 0; d < 32; ++d)
                s = fmaf(qe[d], vnT[d * 33 + j], s);
            if (j <= l) y = fmaf(lg[j] * s, knb[j * 32 + lane], y);
        }
        y *= lwgt[l];
        ctxt[((size_t)(b * Ls + c * T + l)) * 256 + h * 32 + lane] = y;
    }
}

extern "C" void kernel_launch(void* const* d_in, const int* in_sizes, int n_in,
                              void* d_out, int out_size, void* d_ws, size_t ws_size,
                              hipStream_t stream) {
    const float* x    = (const float*)d_in[0];
    const float* wq_w = (const float*)d_in[1];
    const float* wq_b = (const float*)d_in[2];
    const float* wk_w = (const float*)d_in[3];
    const float* wk_b = (const float*)d_in[4];
    const float* wv_w = (const float*)d_in[5];
    const float* wv_b = (const float*)d_in[6];
    const float* wo_w = (const float*)d_in[7];
    const float* wo_b = (const float*)d_in[8];
    const float* wg_w = (const float*)d_in[9];
    const float* wg_b = (const float*)d_in[10];
    const float* kvs  = (const float*)d_in[11];
    const float* qks  = (const float*)d_in[12];
    float* out = (float*)d_out;

    float* ws = (float*)d_ws;
    float* qh   = out;                    // d_out doubles as q scratch (1M floats)
    float* kh   = ws;                     // 1048576
    float* vh   = kh + 1048576;           // 1048576
    float* simG = vh + 1048576;           // 32768
    float* gG   = simG + 32768;           // 32768
    float* ZcT  = gG + 32768;             // 16*64*1024 = 1048576
    float* mT   = ZcT + 1048576;          // 1024
    float* sT   = mT + 1024;              // 1024
    float* gTt  = sT + 1024;              // 1024
    float* aW   = gTt + 1024;             // 256
    float* bW   = aW + 256;               // 256
    int*   flagW = (int*)(bW + 256);      // 4 floats reserved
    float* ctxt = bW + 256 + 4;           // 1048576
    // total ~17.1 MB

    gemm_kernel<<<dim3(64, 12), 256, 0, stream>>>(
        x, wq_w, wq_b, wk_w, wk_b, wv_w, wv_b, qh, kh, vh, 0);
    chunk_sum_kernel<<<dim3(NCH, 16), 1024, 0, stream>>>(
        qh, kh, vh, wg_w, wg_b, kvs, qks, simG, gG, ZcT, mT, sT, gTt);
    prefix_kernel<<<dim3(16, 4), 256, 0, stream>>>(
        ZcT, mT, sT, gTt, kvs, aW, bW, flagW);
    chunk_out_kernel<<<dim3(NCH, 16), 1024, 0, stream>>>(
        qh, kh, vh, simG, gG, kvs, ZcT, mT, sT, gTt, aW, bW, flagW, ctxt);
    gemm_kernel<<<dim3(64, 4), 256, 0, stream>>>(
        ctxt, wo_w, wo_b, nullptr, nullptr, nullptr, nullptr, out, nullptr, nullptr, 1);
}

// Round 4
// 147.310 us; speedup vs baseline: 1.4680x; 1.0989x over previous
//
#include <hip/hip_runtime.h>
#include <math.h>

#define EPSV 1e-5f

static constexpr int Ls = 2048, Hh = 8;
static constexpr int NCH = 64, T = 32;   // 64 chunks of 32 along L

typedef unsigned short u16;
using frag  = __attribute__((ext_vector_type(8))) short;   // 8 x bf16 (4 VGPRs)
using f32x4 = __attribute__((ext_vector_type(4))) float;

__device__ __forceinline__ void split_bf16(float v, u16& hi, u16& lo) {
    const unsigned u = __float_as_uint(v);
    hi = (u16)(u >> 16);
    const float hf = __uint_as_float((unsigned)hi << 16);
    lo = (u16)(__float_as_uint(v - hf) >> 16);
}

// ---------------- convert: split x and 4 weights into hi/lo bf16 ----------------
// grid: 1280 x 256, one float4 per thread. x: 262144 f4; each weight: 16384 f4.
__global__ __launch_bounds__(256) void convert_kernel(
    const float* __restrict__ x, const float* __restrict__ wq,
    const float* __restrict__ wk, const float* __restrict__ wv,
    const float* __restrict__ wo,
    u16* __restrict__ xhi, u16* __restrict__ xlo,
    u16* __restrict__ whi, u16* __restrict__ wlo)
{
    const int gi = blockIdx.x * 256 + threadIdx.x;
    const float* src;
    u16 *dhi, *dlo;
    size_t off;
    if (gi < 262144) {
        src = x; off = gi; dhi = xhi; dlo = xlo;
    } else {
        const int t = gi - 262144;
        const int w = t >> 14, o = t & 16383;
        src = w == 0 ? wq : w == 1 ? wk : w == 2 ? wv : wo;
        off = o;
        dhi = whi + (size_t)w * 65536;
        dlo = wlo + (size_t)w * 65536;
    }
    const float4 v = ((const float4*)src)[off];
    ushort4 h, l;
    split_bf16(v.x, h.x, l.x);
    split_bf16(v.y, h.y, l.y);
    split_bf16(v.z, h.z, l.z);
    split_bf16(v.w, h.w, l.w);
    ((ushort4*)dhi)[off] = h;
    ((ushort4*)dlo)[off] = l;
}

// ---------------- MFMA GEMM (split-bf16, 3 products): C = A * W^T + b ----------
// A: [4096][256] hi/lo bf16. W: 4 weights at whi + which*65536, [256][256] hi/lo.
// mode 0: qkv (grid.y = 12, which = nt>>2), head-layout out [b][h][l][e] fp32
// mode 1: out-proj (grid.y = 4, which = 3), plain [m][n] fp32
__global__ __launch_bounds__(256) void mfma_gemm(
    const u16* __restrict__ Ahi, const u16* __restrict__ Alo,
    const u16* __restrict__ Whi_all, const u16* __restrict__ Wlo_all,
    const float* __restrict__ bq, const float* __restrict__ bk, const float* __restrict__ bv,
    float* __restrict__ oq, float* __restrict__ ok_, float* __restrict__ ov,
    int mode)
{
    constexpr int LDK = 40;                 // 32 + 8 bf16 pad = 80 B rows (16B-aligned, 2-way banks)
    __shared__ u16 As_hi[128 * LDK], As_lo[128 * LDK];
    __shared__ u16 Bs_hi[64 * LDK],  Bs_lo[64 * LDK];

    const int tid = threadIdx.x;
    const int mt = blockIdx.x, nt = blockIdx.y;
    int ncol0, which;
    const float* bp;
    float* Op;
    if (mode == 0) {
        which = nt >> 2;
        ncol0 = (nt & 3) * 64;
        bp = which == 0 ? bq : which == 1 ? bk : bv;
        Op = which == 0 ? oq : which == 1 ? ok_ : ov;
    } else {
        which = 3;
        ncol0 = nt * 64;
        bp = bq;
        Op = oq;
    }
    const u16* Whi = Whi_all + (size_t)which * 65536;
    const u16* Wlo = Wlo_all + (size_t)which * 65536;

    const int m0 = mt * 128;
    const int srow = tid >> 2, skc = tid & 3;   // staging: row, 16B k-chunk
    const int wave = tid >> 6, lane = tid & 63;
    const int l15 = lane & 15, quad = lane >> 4;
    const int wm0 = (wave >> 1) * 64, wn0 = (wave & 1) * 32;

    f32x4 acc[4][2] = {};

    for (int k0 = 0; k0 < 256; k0 += 32) {
        const size_t ga0 = (size_t)(m0 + srow) * 256 + k0 + skc * 8;
        const size_t ga1 = (size_t)(m0 + 64 + srow) * 256 + k0 + skc * 8;
        const size_t gb  = (size_t)(ncol0 + srow) * 256 + k0 + skc * 8;
        const uint4 ah0 = *(const uint4*)&Ahi[ga0];
        const uint4 ah1 = *(const uint4*)&Ahi[ga1];
        const uint4 al0 = *(const uint4*)&Alo[ga0];
        const uint4 al1 = *(const uint4*)&Alo[ga1];
        const uint4 bh0 = *(const uint4*)&Whi[gb];
        const uint4 bl0 = *(const uint4*)&Wlo[gb];
        __syncthreads();
        *(uint4*)&As_hi[srow * LDK + skc * 8] = ah0;
        *(uint4*)&As_hi[(64 + srow) * LDK + skc * 8] = ah1;
        *(uint4*)&As_lo[srow * LDK + skc * 8] = al0;
        *(uint4*)&As_lo[(64 + srow) * LDK + skc * 8] = al1;
        *(uint4*)&Bs_hi[srow * LDK + skc * 8] = bh0;
        *(uint4*)&Bs_lo[srow * LDK + skc * 8] = bl0;
        __syncthreads();

        frag ah[4], al[4], bh[2], bl[2];
#pragma unroll
        for (int tm = 0; tm < 4; ++tm) {
            const int r = wm0 + tm * 16 + l15;
            ah[tm] = *(const frag*)&As_hi[r * LDK + quad * 8];
            al[tm] = *(const frag*)&As_lo[r * LDK + quad * 8];
        }
#pragma unroll
        for (int tn = 0; tn < 2; ++tn) {
            const int r = wn0 + tn * 16 + l15;
            bh[tn] = *(const frag*)&Bs_hi[r * LDK + quad * 8];
            bl[tn] = *(const frag*)&Bs_lo[r * LDK + quad * 8];
        }
#pragma unroll
        for (int tm = 0; tm < 4; ++tm)
#pragma unroll
            for (int tn = 0; tn < 2; ++tn) {
                acc[tm][tn] = __builtin_amdgcn_mfma_f32_16x16x32_bf16(ah[tm], bh[tn], acc[tm][tn], 0, 0, 0);
                acc[tm][tn] = __builtin_amdgcn_mfma_f32_16x16x32_bf16(ah[tm], bl[tn], acc[tm][tn], 0, 0, 0);
                acc[tm][tn] = __builtin_amdgcn_mfma_f32_16x16x32_bf16(al[tm], bh[tn], acc[tm][tn], 0, 0, 0);
            }
    }

#pragma unroll
    for (int tn = 0; tn < 2; ++tn) {
        const int o = ncol0 + wn0 + tn * 16 + l15;
        const float bias = bp[o];
        const int hd = o >> 5, e = o & 31;
#pragma unroll
        for (int tm = 0; tm < 4; ++tm)
#pragma unroll
            for (int r = 0; r < 4; ++r) {
                const int rm = m0 + wm0 + tm * 16 + quad * 4 + r;
                const float val = acc[tm][tn][r] + bias;
                if (mode == 0) {
                    const int b = rm >> 11, l = rm & (Ls - 1);
                    Op[(((size_t)(b * Hh + hd)) * Ls + l) * 32 + e] = val;
                } else {
                    Op[(size_t)rm * 256 + o] = val;
                }
            }
    }
}

// ---------------- chunk_sum: normalize k/v (in place), sim, gates, chunk totals ----
__global__ __launch_bounds__(1024) void chunk_sum_kernel(
    const float* __restrict__ qh, float* __restrict__ kh, float* __restrict__ vh,
    const float* __restrict__ wg_w, const float* __restrict__ wg_b,
    const float* __restrict__ kvs, const float* __restrict__ qks,
    float* __restrict__ simG, float* __restrict__ gG,
    float* __restrict__ ZcT, float* __restrict__ mT, float* __restrict__ sT,
    float* __restrict__ gTt)
{
    __shared__ float lkn[1024], lvn[1024], lwk[1024], lsim[T], lg[T];
    const int tid = threadIdx.x;
    const int c = blockIdx.x, bh = blockIdx.y, h = bh & 7;
    const int l = tid >> 5, lane = tid & 31;
    const size_t base = ((size_t)bh * Ls + c * T) * 32;

    const float qv = qh[base + tid];
    const float kv = kh[base + tid];
    const float vv = vh[base + tid];
    lwk[tid] = wg_w[tid] * kvs[h * 1024 + tid];

    float qk = qv * kv, ks = kv * kv, vs = vv * vv;
#pragma unroll
    for (int off = 16; off; off >>= 1) {
        qk += __shfl_xor(qk, off);
        ks += __shfl_xor(ks, off);
        vs += __shfl_xor(vs, off);
    }
    const float kn = kv / fmaxf(sqrtf(ks), 1e-12f);
    const float vn = vv / fmaxf(sqrtf(vs), 1e-12f);
    kh[base + tid] = kn;
    vh[base + tid] = vn;
    lkn[tid] = kn;
    lvn[tid] = vn;
    if (lane == 0) {
        const float s = qk * qks[h];
        lsim[l] = s;
        simG[bh * Ls + c * T + l] = s;
    }
    __syncthreads();

    float t = 0.f;
#pragma unroll 8
    for (int d = 0; d < 32; ++d)
        t = fmaf(lvn[l * 32 + d], lwk[d * 32 + lane], t);
    t *= lkn[l * 32 + lane];
#pragma unroll
    for (int off = 16; off; off >>= 1) t += __shfl_xor(t, off);
    if (lane == 0) {
        const float r = fmaxf(t + wg_b[0], 0.f);
        const float g = r * r + EPSV;
        lg[l] = g;
        gG[bh * Ls + c * T + l] = g;
    }
    __syncthreads();

    {
        const int e = tid & 31, d = tid >> 5;
        float z = 0.f;
#pragma unroll 8
        for (int l2 = 0; l2 < T; ++l2)
            z = fmaf(lg[l2] * lvn[l2 * 32 + d], lkn[l2 * 32 + e], z);
        ZcT[((size_t)bh * NCH + c) * 1024 + tid] = z;
    }

    if (tid < 32) {
        float m = lsim[tid], s = 1.f, g = lg[tid];
#pragma unroll
        for (int off = 16; off; off >>= 1) {
            const float mo = __shfl_xor(m, off);
            const float so = __shfl_xor(s, off);
            const float mn = fmaxf(m, mo);
            s = s * __expf(m - mn) + so * __expf(mo - mn);
            m = mn;
            g += __shfl_xor(g, off);
        }
        if (tid == 0) {
            mT[bh * NCH + c] = m;
            sT[bh * NCH + c] = s;
            gTt[bh * NCH + c] = g;
        }
    }
}

// ---------------- prefix: exclusive prefixes over chunks + rank-1 setup ----------
__global__ __launch_bounds__(256) void prefix_kernel(
    float* __restrict__ Zc, float* __restrict__ mT, float* __restrict__ sT,
    float* __restrict__ gTt,
    const float* __restrict__ kvs, float* __restrict__ aW, float* __restrict__ bW,
    int* __restrict__ flagW)
{
    const int bh = blockIdx.x, seg = blockIdx.y;
    const int tid = threadIdx.x;
    const int el = seg * 256 + tid;
    float* Zb = Zc + (size_t)bh * NCH * 1024 + el;

    float run = 0.f;
#pragma unroll
    for (int cb = 0; cb < NCH; cb += 8) {
        float v[8];
#pragma unroll
        for (int i = 0; i < 8; ++i) v[i] = Zb[(size_t)(cb + i) * 1024];
#pragma unroll
        for (int i = 0; i < 8; ++i) {
            const float t = v[i];
            Zb[(size_t)(cb + i) * 1024] = run;
            run += t;
        }
    }

    if (seg == 0 && tid < 64) {
        float m = mT[bh * NCH + tid], s = sT[bh * NCH + tid], g = gTt[bh * NCH + tid];
#pragma unroll
        for (int off = 1; off < 64; off <<= 1) {
            const float mo = __shfl_up(m, off);
            const float so = __shfl_up(s, off);
            const float go = __shfl_up(g, off);
            if (tid >= off) {
                const float mn = fmaxf(m, mo);
                s = s * __expf(m - mn) + so * __expf(mo - mn);
                m = mn;
                g += go;
            }
        }
        float me = __shfl_up(m, 1), se = __shfl_up(s, 1), ge = __shfl_up(g, 1);
        if (tid == 0) { me = -1e30f; se = 0.f; ge = 0.f; }
        mT[bh * NCH + tid] = me;
        sT[bh * NCH + tid] = se;
        gTt[bh * NCH + tid] = ge;
    }

    if (bh == 0 && seg == 3) {
        const int h = tid >> 5, e = tid & 31;
        const float* K = kvs + h * 1024;
        const float k00 = K[0];
        int ok = (k00 != 0.0f);
        for (int d = 0; d < 32; ++d) {
            const float lhs = K[d * 32 + e] * k00;
            const float rhs = K[d * 32] * K[e];
            const float diff = fabsf(lhs - rhs);
            if (diff > 1e-6f * fmaxf(fmaxf(fabsf(lhs), fabsf(rhs)), 1e-20f)) ok = 0;
        }
        aW[h * 32 + e] = K[e * 32];
        bW[h * 32 + e] = (k00 != 0.0f) ? K[e] / k00 : 0.f;
        const int allok = __syncthreads_and(ok);
        if (tid == 0) flagW[0] = allok;
    }
}

// ---------------- chunk_out: matmul-shaped replay, emit ctxt as hi/lo bf16 ----------
__global__ __launch_bounds__(1024) void chunk_out_kernel(
    const float* __restrict__ qh, const float* __restrict__ knG, const float* __restrict__ vnG,
    const float* __restrict__ simG, const float* __restrict__ gG,
    const float* __restrict__ kvs,
    const float* __restrict__ ZcP, const float* __restrict__ mP,
    const float* __restrict__ sP, const float* __restrict__ gP,
    const float* __restrict__ aW, const float* __restrict__ bW,
    const int* __restrict__ flagW,
    u16* __restrict__ chi, u16* __restrict__ clo)
{
    __shared__ float qa[1024], knb[1024], zp[1024], lkvs[1024];
    __shared__ float vnT[32 * 33], sW[32 * 33];
    __shared__ float la[32], lb[32], lg[T], lsim[T], lwgt[T];
    const int tid = threadIdx.x;
    const int c = blockIdx.x, bh = blockIdx.y, h = bh & 7, b = bh >> 3;
    const int l = tid >> 5, lane = tid & 31;
    const size_t base = ((size_t)bh * Ls + c * T) * 32;
    const int flag = flagW[0];

    const float qv = qh[base + tid];
    const float knv = knG[base + tid];
    const float vnv = vnG[base + tid];
    vnT[lane * 33 + l] = vnv;
    zp[tid] = ZcP[((size_t)bh * NCH + c) * 1024 + tid];
    if (!flag) lkvs[tid] = kvs[h * 1024 + tid];
    if (tid < 32) {
        la[tid] = aW[h * 32 + tid];
        lb[tid] = bW[h * 32 + tid];
        lg[tid] = gG[bh * Ls + c * T + tid];
        lsim[tid] = simG[bh * Ls + c * T + tid];
    }
    __syncthreads();

    qa[tid] = flag ? qv * la[lane] : qv;
    knb[tid] = flag ? knv * lb[lane] : knv;
    if (tid < 32) {
        float m = lsim[tid], s = 1.f, g = lg[tid];
#pragma unroll
        for (int off = 1; off < 32; off <<= 1) {
            const float mo = __shfl_up(m, off);
            const float so = __shfl_up(s, off);
            const float go = __shfl_up(g, off);
            if (tid >= off) {
                const float mn = fmaxf(m, mo);
                s = s * __expf(m - mn) + so * __expf(mo - mn);
                m = mn;
                g += go;
            }
        }
        const float mp = mP[bh * NCH + c];
        const float sp = sP[bh * NCH + c];
        const float gp = gP[bh * NCH + c];
        const float mn = fmaxf(mp, m);
        s = sp * __expf(mp - mn) + s * __expf(m - mn);
        m = mn;
        g += gp;
        const float sw = __expf(lsim[tid] - m) / (s + EPSV);
        const float sig = 1.f / (1.f + __expf(-sw));
        lwgt[tid] = (1.f + sw * sig) / (g + EPSV);
    }
    __syncthreads();

    float y;
    if (flag) {
        float s = 0.f, y0 = 0.f;
        const float4* qa4 = (const float4*)&qa[l * 32];
#pragma unroll
        for (int d4 = 0; d4 < 8; ++d4) {
            const float4 q4 = qa4[d4];
            const int d = d4 * 4;
            s = fmaf(q4.x, vnT[(d + 0) * 33 + lane], s);
            s = fmaf(q4.y, vnT[(d + 1) * 33 + lane], s);
            s = fmaf(q4.z, vnT[(d + 2) * 33 + lane], s);
            s = fmaf(q4.w, vnT[(d + 3) * 33 + lane], s);
            y0 = fmaf(q4.x, zp[(d + 0) * 32 + lane], y0);
            y0 = fmaf(q4.y, zp[(d + 1) * 32 + lane], y0);
            y0 = fmaf(q4.z, zp[(d + 2) * 32 + lane], y0);
            y0 = fmaf(q4.w, zp[(d + 3) * 32 + lane], y0);
        }
        sW[l * 33 + lane] = (lane <= l) ? lg[lane] * s : 0.f;
        __syncthreads();
        y = y0 * lb[lane];
#pragma unroll 8
        for (int j = 0; j < 32; ++j)
            y = fmaf(sW[l * 33 + j], knb[j * 32 + lane], y);
        y *= lwgt[l];
    } else {
        float qe[32];
#pragma unroll
        for (int d = 0; d < 32; ++d)
            qe[d] = qa[l * 32 + d] * lkvs[d * 32 + lane];
        y = 0.f;
#pragma unroll
        for (int d = 0; d < 32; ++d)
            y = fmaf(qe[d], zp[d * 32 + lane], y);
        for (int j = 0; j < 32; ++j) {
            float s = 0.f;
#pragma unroll
            for (int d = 0; d < 32; ++d)
                s = fmaf(qe[d], vnT[d * 33 + j], s);
            if (j <= l) y = fmaf(lg[j] * s, knb[j * 32 + lane], y);
        }
        y *= lwgt[l];
    }
    u16 hi, lo;
    split_bf16(y, hi, lo);
    const size_t oidx = ((size_t)(b * Ls + c * T + l)) * 256 + h * 32 + lane;
    chi[oidx] = hi;
    clo[oidx] = lo;
}

extern "C" void kernel_launch(void* const* d_in, const int* in_sizes, int n_in,
                              void* d_out, int out_size, void* d_ws, size_t ws_size,
                              hipStream_t stream) {
    const float* x    = (const float*)d_in[0];
    const float* wq_w = (const float*)d_in[1];
    const float* wq_b = (const float*)d_in[2];
    const float* wk_w = (const float*)d_in[3];
    const float* wk_b = (const float*)d_in[4];
    const float* wv_w = (const float*)d_in[5];
    const float* wv_b = (const float*)d_in[6];
    const float* wo_w = (const float*)d_in[7];
    const float* wo_b = (const float*)d_in[8];
    const float* wg_w = (const float*)d_in[9];
    const float* wg_b = (const float*)d_in[10];
    const float* kvs  = (const float*)d_in[11];
    const float* qks  = (const float*)d_in[12];
    float* out = (float*)d_out;

    u16* xhi = (u16*)d_ws;                 // 1048576
    u16* xlo = xhi + 1048576;              // 1048576
    u16* whi = xlo + 1048576;              // 4 * 65536
    u16* wlo = whi + 262144;               // 4 * 65536
    u16* chi = wlo + 262144;               // 1048576
    u16* clo = chi + 1048576;              // 1048576
    float* qh   = (float*)(clo + 1048576); // fp32 from here (8B-aligned: even u16 count)
    float* kh   = qh + 1048576;
    float* vh   = kh + 1048576;
    float* ZcT  = vh + 1048576;            // 1048576
    float* simG = ZcT + 1048576;           // 32768
    float* gG   = simG + 32768;            // 32768
    float* mT   = gG + 32768;              // 1024
    float* sT   = mT + 1024;
    float* gTt  = sT + 1024;
    float* aW   = gTt + 1024;              // 256
    float* bW   = aW + 256;                // 256
    int* flagW  = (int*)(bW + 256);
    // total ~25.6 MB

    convert_kernel<<<1280, 256, 0, stream>>>(
        x, wq_w, wk_w, wv_w, wo_w, xhi, xlo, whi, wlo);
    mfma_gemm<<<dim3(32, 12), 256, 0, stream>>>(
        xhi, xlo, whi, wlo, wq_b, wk_b, wv_b, qh, kh, vh, 0);
    chunk_sum_kernel<<<dim3(NCH, 16), 1024, 0, stream>>>(
        qh, kh, vh, wg_w, wg_b, kvs, qks, simG, gG, ZcT, mT, sT, gTt);
    prefix_kernel<<<dim3(16, 4), 256, 0, stream>>>(
        ZcT, mT, sT, gTt, kvs, aW, bW, flagW);
    chunk_out_kernel<<<dim3(NCH, 16), 1024, 0, stream>>>(
        qh, kh, vh, simG, gG, kvs, ZcT, mT, sT, gTt, aW, bW, flagW, chi, clo);
    mfma_gemm<<<dim3(32, 4), 256, 0, stream>>>(
        chi, clo, whi, wlo, wo_b, nullptr, nullptr, out, nullptr, nullptr, 1);
}

// Round 5
// 145.177 us; speedup vs baseline: 1.4896x; 1.0147x over previous
//
#include <hip/hip_runtime.h>
#include <math.h>

#define EPSV 1e-5f

static constexpr int Ls = 2048, Hh = 8;
static constexpr int NCH = 64, T = 32;   // 64 chunks of 32 along L

typedef unsigned short u16;
using frag  = __attribute__((ext_vector_type(8))) short;   // 8 x bf16 (4 VGPRs)
using f32x4 = __attribute__((ext_vector_type(4))) float;

__device__ __forceinline__ void split_bf16(float v, u16& hi, u16& lo) {
    const unsigned u = __float_as_uint(v);
    hi = (u16)(u >> 16);
    const float hf = __uint_as_float((unsigned)hi << 16);
    lo = (u16)(__float_as_uint(v - hf) >> 16);
}

__device__ __forceinline__ unsigned pk2(u16 a, u16 b) {
    return (unsigned)a | ((unsigned)b << 16);
}

// split 8 fp32 into one uint4 of hi-bf16 and one uint4 of lo-bf16
__device__ __forceinline__ void split8(const float4& a, const float4& b,
                                       uint4& hi, uint4& lo) {
    u16 h[8], l[8];
    const float f[8] = {a.x, a.y, a.z, a.w, b.x, b.y, b.z, b.w};
#pragma unroll
    for (int i = 0; i < 8; ++i) split_bf16(f[i], h[i], l[i]);
    hi = make_uint4(pk2(h[0], h[1]), pk2(h[2], h[3]), pk2(h[4], h[5]), pk2(h[6], h[7]));
    lo = make_uint4(pk2(l[0], l[1]), pk2(l[2], l[3]), pk2(l[4], l[5]), pk2(l[6], l[7]));
}

// =====================================================================
// qkv_fused: split-bf16 MFMA GEMM for q,k,v (64 rows x 2 heads per block)
// + fused chunk_sum epilogue (normalize, sim, gate, chunk-Z, (m,s,g) totals)
// grid: (64 row-tiles, 4 head-pairs) x 256 threads (4 waves)
// =====================================================================
__global__ __launch_bounds__(256) void qkv_fused(
    const float* __restrict__ x,
    const float* __restrict__ wq, const float* __restrict__ wk, const float* __restrict__ wv,
    const float* __restrict__ bq, const float* __restrict__ bk, const float* __restrict__ bv,
    const float* __restrict__ wg_w, const float* __restrict__ wg_b,
    const float* __restrict__ kvs, const float* __restrict__ qks,
    float* __restrict__ qh, float* __restrict__ kh, float* __restrict__ vh,
    float* __restrict__ simG, float* __restrict__ gG,
    float* __restrict__ ZcT, float* __restrict__ mT, float* __restrict__ sT,
    float* __restrict__ gTt)
{
    constexpr int LDK = 40;     // u16 per staged row (80 B, 16B-aligned)
    constexpr int LDT = 66;     // f32 per tile row (264 B: 8B-aligned, 2-way banks)
    // staging (40960 B) and tiles (50688 B) alias; phases separated by barriers
    __shared__ __align__(16) float smemf[3 * 64 * LDT];
    __shared__ float wkS[2][1024];
    __shared__ float lsim[2][64], lg2[2][64];

    u16* As_hi = (u16*)smemf;          // 2560 u16
    u16* As_lo = As_hi + 2560;
    u16* Wst   = As_lo + 2560;         // per weight w: hi at w*5120, lo at +2560
    float* Qt = smemf;
    float* Kt = Qt + 64 * LDT;
    float* Vt = Kt + 64 * LDT;

    const int tid = threadIdx.x;
    const int mt = blockIdx.x, nt = blockIdx.y;
    const int m0 = mt * 64, ncol0 = nt * 64;
    const int bidx = m0 >> 11, lg = m0 & (Ls - 1);
    const int wave = tid >> 6, lane = tid & 63;
    const int l15 = lane & 15, quad = lane >> 4;
    const int srow = tid >> 2, sk = (tid & 3) * 8;

    // wg_w * kvs for this block's two heads
    for (int i = tid; i < 2048; i += 256) {
        const int h = i >> 10, de = i & 1023;
        wkS[h][de] = wg_w[de] * kvs[(nt * 2 + h) * 1024 + de];
    }

    const float* Wsrc[3] = {wq, wk, wv};
    f32x4 acc[3][4] = {};

    for (int k0 = 0; k0 < 256; k0 += 32) {
        const float4 a0 = *(const float4*)&x[(size_t)(m0 + srow) * 256 + k0 + sk];
        const float4 a1 = *(const float4*)&x[(size_t)(m0 + srow) * 256 + k0 + sk + 4];
        float4 w0[3], w1[3];
#pragma unroll
        for (int w = 0; w < 3; ++w) {
            w0[w] = *(const float4*)&Wsrc[w][(size_t)(ncol0 + srow) * 256 + k0 + sk];
            w1[w] = *(const float4*)&Wsrc[w][(size_t)(ncol0 + srow) * 256 + k0 + sk + 4];
        }
        __syncthreads();
        {
            uint4 hi, lo;
            split8(a0, a1, hi, lo);
            *(uint4*)&As_hi[srow * LDK + sk] = hi;
            *(uint4*)&As_lo[srow * LDK + sk] = lo;
#pragma unroll
            for (int w = 0; w < 3; ++w) {
                split8(w0[w], w1[w], hi, lo);
                *(uint4*)&Wst[w * 5120 + srow * LDK + sk] = hi;
                *(uint4*)&Wst[w * 5120 + 2560 + srow * LDK + sk] = lo;
            }
        }
        __syncthreads();

        const frag ah = *(const frag*)&As_hi[(wave * 16 + l15) * LDK + quad * 8];
        const frag al = *(const frag*)&As_lo[(wave * 16 + l15) * LDK + quad * 8];
#pragma unroll
        for (int w = 0; w < 3; ++w)
#pragma unroll
            for (int cf = 0; cf < 4; ++cf) {
                const u16* bp = &Wst[w * 5120 + (cf * 16 + l15) * LDK + quad * 8];
                const frag bh = *(const frag*)bp;
                const frag bl = *(const frag*)(bp + 2560);
                acc[w][cf] = __builtin_amdgcn_mfma_f32_16x16x32_bf16(ah, bh, acc[w][cf], 0, 0, 0);
                acc[w][cf] = __builtin_amdgcn_mfma_f32_16x16x32_bf16(ah, bl, acc[w][cf], 0, 0, 0);
                acc[w][cf] = __builtin_amdgcn_mfma_f32_16x16x32_bf16(al, bh, acc[w][cf], 0, 0, 0);
            }
    }
    __syncthreads();   // staging dead; write tiles (aliased region)

    {
        float* tiles[3] = {Qt, Kt, Vt};
        const float* biases[3] = {bq, bk, bv};
#pragma unroll
        for (int w = 0; w < 3; ++w)
#pragma unroll
            for (int cf = 0; cf < 4; ++cf) {
                const int col = cf * 16 + l15;
                const float bias = biases[w][ncol0 + col];
#pragma unroll
                for (int r = 0; r < 4; ++r) {
                    const int m = wave * 16 + quad * 4 + r;
                    tiles[w][m * LDT + col] = acc[w][cf][r] + bias;
                }
            }
    }
    __syncthreads();

    // ---- Phase N: per (h,l) normalize k,v in place; sim ----
    if (tid < 128) {
        const int h = tid >> 6, l = tid & 63;
        const int cb = h * 32;
        float ksum = 0.f, vsum = 0.f, qk = 0.f;
#pragma unroll 8
        for (int e = 0; e < 32; ++e) {
            const float kv = Kt[l * LDT + cb + e];
            const float vv = Vt[l * LDT + cb + e];
            const float qv = Qt[l * LDT + cb + e];
            ksum = fmaf(kv, kv, ksum);
            vsum = fmaf(vv, vv, vsum);
            qk = fmaf(qv, kv, qk);
        }
        const float kscale = 1.f / fmaxf(sqrtf(ksum), 1e-12f);
        const float vscale = 1.f / fmaxf(sqrtf(vsum), 1e-12f);
#pragma unroll 8
        for (int e = 0; e < 32; ++e) {
            Kt[l * LDT + cb + e] *= kscale;
            Vt[l * LDT + cb + e] *= vscale;
        }
        const float sim = qk * qks[nt * 2 + h];
        lsim[h][l] = sim;
        simG[(size_t)(bidx * 8 + nt * 2 + h) * Ls + lg + l] = sim;
    }
    __syncthreads();

    // ---- Phase copy: q, kn, vn to global (coalesced float2) ----
    {
        const float* tl[3] = {Qt, Kt, Vt};
        float* gl[3] = {qh, kh, vh};
#pragma unroll
        for (int arr = 0; arr < 3; ++arr)
#pragma unroll
            for (int it = 0; it < 8; ++it) {
                const int idx = it * 512 + tid * 2;
                const int h = idx >> 11, rem = idx & 2047;
                const int l = rem >> 5, e = rem & 31;
                float2 v;
                v.x = tl[arr][l * LDT + h * 32 + e];
                v.y = tl[arr][l * LDT + h * 32 + e + 1];
                *(float2*)&gl[arr][(size_t)(bidx * 8 + nt * 2 + h) * 65536 +
                                   (size_t)(lg + l) * 32 + e] = v;
            }
    }

    // ---- Phase G: gate per (h,l); 2 threads per task ----
    {
        const int task = tid >> 1, half = tid & 1;
        const int h = task >> 6, l = task & 63;
        float vreg[32];
#pragma unroll 8
        for (int d = 0; d < 32; ++d) vreg[d] = Vt[l * LDT + h * 32 + d];
        float u = 0.f;
        const int e0 = half * 16;
#pragma unroll 4
        for (int e = e0; e < e0 + 16; ++e) {
            float s = 0.f;
#pragma unroll 8
            for (int d = 0; d < 32; ++d)
                s = fmaf(vreg[d], wkS[h][d * 32 + e], s);
            u = fmaf(s, Kt[l * LDT + h * 32 + e], u);
        }
        u += __shfl_xor(u, 1);
        if (half == 0) {
            const float r = fmaxf(u + wg_b[0], 0.f);
            const float g = r * r + EPSV;
            lg2[h][l] = g;
            gG[(size_t)(bidx * 8 + nt * 2 + h) * Ls + lg + l] = g;
        }
    }
    __syncthreads();

    // ---- Phase Z: chunk-Z totals (2 heads x 2 chunks of 32) ----
    {
        const int d = tid >> 3, e0 = (tid & 7) * 4;
#pragma unroll
        for (int h = 0; h < 2; ++h)
#pragma unroll
            for (int cc = 0; cc < 2; ++cc) {
                float z0 = 0.f, z1 = 0.f, z2 = 0.f, z3 = 0.f;
#pragma unroll 8
                for (int l = 0; l < 32; ++l) {
                    const int lr = cc * 32 + l;
                    const float gv = lg2[h][lr] * Vt[lr * LDT + h * 32 + d];
                    z0 = fmaf(gv, Kt[lr * LDT + h * 32 + e0 + 0], z0);
                    z1 = fmaf(gv, Kt[lr * LDT + h * 32 + e0 + 1], z1);
                    z2 = fmaf(gv, Kt[lr * LDT + h * 32 + e0 + 2], z2);
                    z3 = fmaf(gv, Kt[lr * LDT + h * 32 + e0 + 3], z3);
                }
                const int bhg = bidx * 8 + nt * 2 + h;
                const int cg = (lg >> 5) + cc;
                float4 zv; zv.x = z0; zv.y = z1; zv.z = z2; zv.w = z3;
                *(float4*)&ZcT[((size_t)bhg * NCH + cg) * 1024 + d * 32 + e0] = zv;
            }
    }

    // ---- (m,s,g) chunk totals: wave w handles (h = w>>1, cc = w&1) ----
    {
        const int h = wave >> 1, cc = wave & 1;
        if (lane < 32) {
            const int lr = cc * 32 + lane;
            float m = lsim[h][lr], s = 1.f, g = lg2[h][lr];
#pragma unroll
            for (int off = 16; off; off >>= 1) {
                const float mo = __shfl_xor(m, off);
                const float so = __shfl_xor(s, off);
                const float mn = fmaxf(m, mo);
                s = s * __expf(m - mn) + so * __expf(mo - mn);
                m = mn;
                g += __shfl_xor(g, off);
            }
            if (lane == 0) {
                const int bhg = bidx * 8 + nt * 2 + h;
                const int cg = (lg >> 5) + cc;
                mT[bhg * NCH + cg] = m;
                sT[bhg * NCH + cg] = s;
                gTt[bhg * NCH + cg] = g;
            }
        }
    }
}

// ---------------- prefix: exclusive prefixes over chunks + rank-1 setup ----------
__global__ __launch_bounds__(256) void prefix_kernel(
    float* __restrict__ Zc, float* __restrict__ mT, float* __restrict__ sT,
    float* __restrict__ gTt,
    const float* __restrict__ kvs, float* __restrict__ aW, float* __restrict__ bW,
    int* __restrict__ flagW)
{
    const int bh = blockIdx.x, seg = blockIdx.y;
    const int tid = threadIdx.x;
    const int el = seg * 256 + tid;
    float* Zb = Zc + (size_t)bh * NCH * 1024 + el;

    float run = 0.f;
#pragma unroll
    for (int cb = 0; cb < NCH; cb += 8) {
        float v[8];
#pragma unroll
        for (int i = 0; i < 8; ++i) v[i] = Zb[(size_t)(cb + i) * 1024];
#pragma unroll
        for (int i = 0; i < 8; ++i) {
            const float t = v[i];
            Zb[(size_t)(cb + i) * 1024] = run;
            run += t;
        }
    }

    if (seg == 0 && tid < 64) {
        float m = mT[bh * NCH + tid], s = sT[bh * NCH + tid], g = gTt[bh * NCH + tid];
#pragma unroll
        for (int off = 1; off < 64; off <<= 1) {
            const float mo = __shfl_up(m, off);
            const float so = __shfl_up(s, off);
            const float go = __shfl_up(g, off);
            if (tid >= off) {
                const float mn = fmaxf(m, mo);
                s = s * __expf(m - mn) + so * __expf(mo - mn);
                m = mn;
                g += go;
            }
        }
        float me = __shfl_up(m, 1), se = __shfl_up(s, 1), ge = __shfl_up(g, 1);
        if (tid == 0) { me = -1e30f; se = 0.f; ge = 0.f; }
        mT[bh * NCH + tid] = me;
        sT[bh * NCH + tid] = se;
        gTt[bh * NCH + tid] = ge;
    }

    if (bh == 0 && seg == 3) {
        const int h = tid >> 5, e = tid & 31;
        const float* K = kvs + h * 1024;
        const float k00 = K[0];
        int ok = (k00 != 0.0f);
        for (int d = 0; d < 32; ++d) {
            const float lhs = K[d * 32 + e] * k00;
            const float rhs = K[d * 32] * K[e];
            const float diff = fabsf(lhs - rhs);
            if (diff > 1e-6f * fmaxf(fmaxf(fabsf(lhs), fabsf(rhs)), 1e-20f)) ok = 0;
        }
        aW[h * 32 + e] = K[e * 32];
        bW[h * 32 + e] = (k00 != 0.0f) ? K[e] / k00 : 0.f;
        const int allok = __syncthreads_and(ok);
        if (tid == 0) flagW[0] = allok;
    }
}

// ---------------- chunk_out: matmul-shaped replay, emit ctxt as hi/lo bf16 ----------
__global__ __launch_bounds__(1024) void chunk_out_kernel(
    const float* __restrict__ qh, const float* __restrict__ knG, const float* __restrict__ vnG,
    const float* __restrict__ simG, const float* __restrict__ gG,
    const float* __restrict__ kvs,
    const float* __restrict__ ZcP, const float* __restrict__ mP,
    const float* __restrict__ sP, const float* __restrict__ gP,
    const float* __restrict__ aW, const float* __restrict__ bW,
    const int* __restrict__ flagW,
    u16* __restrict__ chi, u16* __restrict__ clo)
{
    __shared__ float qa[1024], knb[1024], zp[1024], lkvs[1024];
    __shared__ float vnT[32 * 33], sW[32 * 33];
    __shared__ float la[32], lb[32], lg[T], lsim[T], lwgt[T];
    const int tid = threadIdx.x;
    const int c = blockIdx.x, bh = blockIdx.y, h = bh & 7, b = bh >> 3;
    const int l = tid >> 5, lane = tid & 31;
    const size_t base = ((size_t)bh * Ls + c * T) * 32;
    const int flag = flagW[0];

    const float qv = qh[base + tid];
    const float knv = knG[base + tid];
    const float vnv = vnG[base + tid];
    vnT[lane * 33 + l] = vnv;
    zp[tid] = ZcP[((size_t)bh * NCH + c) * 1024 + tid];
    if (!flag) lkvs[tid] = kvs[h * 1024 + tid];
    if (tid < 32) {
        la[tid] = aW[h * 32 + tid];
        lb[tid] = bW[h * 32 + tid];
        lg[tid] = gG[bh * Ls + c * T + tid];
        lsim[tid] = simG[bh * Ls + c * T + tid];
    }
    __syncthreads();

    qa[tid] = flag ? qv * la[lane] : qv;
    knb[tid] = flag ? knv * lb[lane] : knv;
    if (tid < 32) {
        float m = lsim[tid], s = 1.f, g = lg[tid];
#pragma unroll
        for (int off = 1; off < 32; off <<= 1) {
            const float mo = __shfl_up(m, off);
            const float so = __shfl_up(s, off);
            const float go = __shfl_up(g, off);
            if (tid >= off) {
                const float mn = fmaxf(m, mo);
                s = s * __expf(m - mn) + so * __expf(mo - mn);
                m = mn;
                g += go;
            }
        }
        const float mp = mP[bh * NCH + c];
        const float sp = sP[bh * NCH + c];
        const float gp = gP[bh * NCH + c];
        const float mn = fmaxf(mp, m);
        s = sp * __expf(mp - mn) + s * __expf(m - mn);
        m = mn;
        g += gp;
        const float sw = __expf(lsim[tid] - m) / (s + EPSV);
        const float sig = 1.f / (1.f + __expf(-sw));
        lwgt[tid] = (1.f + sw * sig) / (g + EPSV);
    }
    __syncthreads();

    float y;
    if (flag) {
        float s = 0.f, y0 = 0.f;
        const float4* qa4 = (const float4*)&qa[l * 32];
#pragma unroll
        for (int d4 = 0; d4 < 8; ++d4) {
            const float4 q4 = qa4[d4];
            const int d = d4 * 4;
            s = fmaf(q4.x, vnT[(d + 0) * 33 + lane], s);
            s = fmaf(q4.y, vnT[(d + 1) * 33 + lane], s);
            s = fmaf(q4.z, vnT[(d + 2) * 33 + lane], s);
            s = fmaf(q4.w, vnT[(d + 3) * 33 + lane], s);
            y0 = fmaf(q4.x, zp[(d + 0) * 32 + lane], y0);
            y0 = fmaf(q4.y, zp[(d + 1) * 32 + lane], y0);
            y0 = fmaf(q4.z, zp[(d + 2) * 32 + lane], y0);
            y0 = fmaf(q4.w, zp[(d + 3) * 32 + lane], y0);
        }
        sW[l * 33 + lane] = (lane <= l) ? lg[lane] * s : 0.f;
        __syncthreads();
        y = y0 * lb[lane];
#pragma unroll 8
        for (int j = 0; j < 32; ++j)
            y = fmaf(sW[l * 33 + j], knb[j * 32 + lane], y);
        y *= lwgt[l];
    } else {
        float qe[32];
#pragma unroll
        for (int d = 0; d < 32; ++d)
            qe[d] = qa[l * 32 + d] * lkvs[d * 32 + lane];
        y = 0.f;
#pragma unroll
        for (int d = 0; d < 32; ++d)
            y = fmaf(qe[d], zp[d * 32 + lane], y);
        for (int j = 0; j < 32; ++j) {
            float s = 0.f;
#pragma unroll
            for (int d = 0; d < 32; ++d)
                s = fmaf(qe[d], vnT[d * 33 + j], s);
            if (j <= l) y = fmaf(lg[j] * s, knb[j * 32 + lane], y);
        }
        y *= lwgt[l];
    }
    u16 hi, lo;
    split_bf16(y, hi, lo);
    const size_t oidx = ((size_t)(b * Ls + c * T + l)) * 256 + h * 32 + lane;
    chi[oidx] = hi;
    clo[oidx] = lo;
}

// ---------------- out_gemm: 64x64-tile split-bf16 MFMA, W split on the fly ----------
__global__ __launch_bounds__(256) void out_gemm(
    const u16* __restrict__ Ahi, const u16* __restrict__ Alo,
    const float* __restrict__ wo, const float* __restrict__ bo,
    float* __restrict__ out)
{
    constexpr int LDK = 40;
    __shared__ __align__(16) u16 As_hi[64 * LDK];
    __shared__ __align__(16) u16 As_lo[64 * LDK];
    __shared__ __align__(16) u16 Ws_hi[64 * LDK];
    __shared__ __align__(16) u16 Ws_lo[64 * LDK];

    const int tid = threadIdx.x;
    const int mt = blockIdx.x, nt = blockIdx.y;
    const int m0 = mt * 64, ncol0 = nt * 64;
    const int wave = tid >> 6, lane = tid & 63;
    const int l15 = lane & 15, quad = lane >> 4;
    const int srow = tid >> 2, sk = (tid & 3) * 8;

    f32x4 acc[4] = {};

    for (int k0 = 0; k0 < 256; k0 += 32) {
        const uint4 ah = *(const uint4*)&Ahi[(size_t)(m0 + srow) * 256 + k0 + sk];
        const uint4 al = *(const uint4*)&Alo[(size_t)(m0 + srow) * 256 + k0 + sk];
        const float4 w0 = *(const float4*)&wo[(size_t)(ncol0 + srow) * 256 + k0 + sk];
        const float4 w1 = *(const float4*)&wo[(size_t)(ncol0 + srow) * 256 + k0 + sk + 4];
        __syncthreads();
        uint4 whi, wlo;
        split8(w0, w1, whi, wlo);
        *(uint4*)&As_hi[srow * LDK + sk] = ah;
        *(uint4*)&As_lo[srow * LDK + sk] = al;
        *(uint4*)&Ws_hi[srow * LDK + sk] = whi;
        *(uint4*)&Ws_lo[srow * LDK + sk] = wlo;
        __syncthreads();

        const frag fah = *(const frag*)&As_hi[(wave * 16 + l15) * LDK + quad * 8];
        const frag fal = *(const frag*)&As_lo[(wave * 16 + l15) * LDK + quad * 8];
#pragma unroll
        for (int cf = 0; cf < 4; ++cf) {
            const frag fbh = *(const frag*)&Ws_hi[(cf * 16 + l15) * LDK + quad * 8];
            const frag fbl = *(const frag*)&Ws_lo[(cf * 16 + l15) * LDK + quad * 8];
            acc[cf] = __builtin_amdgcn_mfma_f32_16x16x32_bf16(fah, fbh, acc[cf], 0, 0, 0);
            acc[cf] = __builtin_amdgcn_mfma_f32_16x16x32_bf16(fah, fbl, acc[cf], 0, 0, 0);
            acc[cf] = __builtin_amdgcn_mfma_f32_16x16x32_bf16(fal, fbh, acc[cf], 0, 0, 0);
        }
    }

#pragma unroll
    for (int cf = 0; cf < 4; ++cf) {
        const int o = ncol0 + cf * 16 + l15;
        const float bias = bo[o];
#pragma unroll
        for (int r = 0; r < 4; ++r) {
            const int rm = m0 + wave * 16 + quad * 4 + r;
            out[(size_t)rm * 256 + o] = acc[cf][r] + bias;
        }
    }
}

extern "C" void kernel_launch(void* const* d_in, const int* in_sizes, int n_in,
                              void* d_out, int out_size, void* d_ws, size_t ws_size,
                              hipStream_t stream) {
    const float* x    = (const float*)d_in[0];
    const float* wq_w = (const float*)d_in[1];
    const float* wq_b = (const float*)d_in[2];
    const float* wk_w = (const float*)d_in[3];
    const float* wk_b = (const float*)d_in[4];
    const float* wv_w = (const float*)d_in[5];
    const float* wv_b = (const float*)d_in[6];
    const float* wo_w = (const float*)d_in[7];
    const float* wo_b = (const float*)d_in[8];
    const float* wg_w = (const float*)d_in[9];
    const float* wg_b = (const float*)d_in[10];
    const float* kvs  = (const float*)d_in[11];
    const float* qks  = (const float*)d_in[12];
    float* out = (float*)d_out;

    u16* chi = (u16*)d_ws;                 // 1048576 u16
    u16* clo = chi + 1048576;              // 1048576 u16
    float* qh   = (float*)(clo + 1048576); // 1048576 f32
    float* kh   = qh + 1048576;
    float* vh   = kh + 1048576;
    float* ZcT  = vh + 1048576;            // 1048576
    float* simG = ZcT + 1048576;           // 32768
    float* gG   = simG + 32768;            // 32768
    float* mT   = gG + 32768;              // 1024
    float* sT   = mT + 1024;
    float* gTt  = sT + 1024;
    float* aW   = gTt + 1024;              // 256
    float* bW   = aW + 256;                // 256
    int* flagW  = (int*)(bW + 256);
    // total ~20.5 MB

    qkv_fused<<<dim3(64, 4), 256, 0, stream>>>(
        x, wq_w, wk_w, wv_w, wq_b, wk_b, wv_b, wg_w, wg_b, kvs, qks,
        qh, kh, vh, simG, gG, ZcT, mT, sT, gTt);
    prefix_kernel<<<dim3(16, 4), 256, 0, stream>>>(
        ZcT, mT, sT, gTt, kvs, aW, bW, flagW);
    chunk_out_kernel<<<dim3(NCH, 16), 1024, 0, stream>>>(
        qh, kh, vh, simG, gG, kvs, ZcT, mT, sT, gTt, aW, bW, flagW, chi, clo);
    out_gemm<<<dim3(64, 4), 256, 0, stream>>>(
        chi, clo, wo_w, wo_b, out);
}